// Round 2
// baseline (145.127 us; speedup 1.0000x reference)
//
#include <hip/hip_runtime.h>
#include <math.h>

#define BATCH 8
#define T 2048
#define N 256        // STATE
#define INF 128      // IN
#define OUTF 128     // OUT
#define L 32         // chunk length (power of 2)
#define LOG2L 5
#define NC (T / L)   // 64 chunks
#define TJ 8         // time tile in K1
#define TT 8         // time tile in K3

// ---------------- K0: stabilize A and build power table A^1..A^L ----------------
__global__ __launch_bounds__(N) void k0_powers(const float* __restrict__ Are,
                                               const float* __restrict__ Aim,
                                               float2* __restrict__ Apow) {
    int n = threadIdx.x;
    float ar = Are[n], ai = Aim[n];
    float m = ar * ar + ai * ai + 1.0f;
    float inv = 1.0f / sqrtf(m);
    ar *= inv; ai *= inv;
    float pr = ar, pi = ai;
    for (int j = 0; j < L; ++j) {
        Apow[j * N + n] = make_float2(pr, pi);   // A^(j+1)
        float nr = pr * ar - pi * ai;
        float ni = pr * ai + pi * ar;
        pr = nr; pi = ni;
    }
}

// ---------------- K1: fused u@B + chunk-local scan ----------------
// grid (NC, BATCH), block 256 (one thread per state n)
__global__ __launch_bounds__(256) void k1_scan(const float* __restrict__ u,
                                               const float* __restrict__ Bre,
                                               const float* __restrict__ Bim,
                                               const float2* __restrict__ Apow,
                                               float2* __restrict__ xbuf,
                                               float2* __restrict__ finals) {
    __shared__ float su[L * INF];   // 32*128*4 = 16 KB
    int c = blockIdx.x, b = blockIdx.y;
    int tid = threadIdx.x;
    const float* ub = u + ((size_t)b * T + (size_t)c * L) * INF;
    for (int idx = tid; idx < L * INF; idx += 256) su[idx] = ub[idx];
    __syncthreads();

    int n = tid;
    float2 a = Apow[n];  // A^1 (stabilized A)
    float xr = 0.f, xi = 0.f;
    float2* xout = xbuf + ((size_t)b * T + (size_t)c * L) * N + n;

    for (int jt = 0; jt < L; jt += TJ) {
        float ubr[TJ], ubi[TJ];
#pragma unroll
        for (int jj = 0; jj < TJ; ++jj) { ubr[jj] = 0.f; ubi[jj] = 0.f; }
        for (int k = 0; k < INF; ++k) {
            float br = Bre[k * N + n];
            float bi = Bim[k * N + n];
#pragma unroll
            for (int jj = 0; jj < TJ; ++jj) {
                float uu = su[(jt + jj) * INF + k];   // wave-uniform -> broadcast
                ubr[jj] += uu * br;
                ubi[jj] += uu * bi;
            }
        }
#pragma unroll
        for (int jj = 0; jj < TJ; ++jj) {
            float nr = a.x * xr - a.y * xi + ubr[jj];
            float ni = a.x * xi + a.y * xr + ubi[jj];
            xr = nr; xi = ni;
            xout[(size_t)(jt + jj) * N] = make_float2(xr, xi);
        }
    }
    finals[((size_t)b * NC + c) * N + n] = make_float2(xr, xi);
}

// ---------------- K2: carry propagation across chunks + x_last output ----------------
// grid BATCH, block 256
// tail_mode: 0 = none, 1 = real-only (out has B*N floats), 2 = interleaved re/im
__global__ __launch_bounds__(256) void k2_carry(const float* __restrict__ x0re,
                                                const float* __restrict__ x0im,
                                                const float2* __restrict__ Apow,
                                                const float2* __restrict__ finals,
                                                float2* __restrict__ prevs,
                                                float* __restrict__ out_tail,
                                                int tail_mode) {
    int b = blockIdx.x, n = threadIdx.x;
    float pr = x0re[b * N + n], pi = x0im[b * N + n];   // x[-1] = x0
    float2 aL = Apow[(L - 1) * N + n];                   // A^L
    for (int c = 0; c < NC; ++c) {
        prevs[((size_t)b * NC + c) * N + n] = make_float2(pr, pi);
        float2 f = finals[((size_t)b * NC + c) * N + n];
        float nr = f.x + aL.x * pr - aL.y * pi;
        float ni = f.y + aL.x * pi + aL.y * pr;
        pr = nr; pi = ni;
    }
    if (tail_mode == 2) {
        // x[:, -1] as complex64 native layout: interleaved re, im
        out_tail[(b * N + n) * 2 + 0] = pr;
        out_tail[(b * N + n) * 2 + 1] = pi;
    } else if (tail_mode == 1) {
        out_tail[b * N + n] = pr;   // real part only
    }
}

// ---------------- K3: correction + y = Re(x@C) + u@D + b ----------------
// grid (T/TT, BATCH), block 128 (one thread per output feature o)
__global__ __launch_bounds__(128) void k3_out(const float2* __restrict__ xbuf,
                                              const float2* __restrict__ Apow,
                                              const float2* __restrict__ prevs,
                                              const float* __restrict__ u,
                                              const float* __restrict__ Cre,
                                              const float* __restrict__ Cim,
                                              const float* __restrict__ D,
                                              const float* __restrict__ bias,
                                              float* __restrict__ y) {
    __shared__ float sxr[TT][N];
    __shared__ float sxi[TT][N];
    __shared__ float su2[TT][INF];
    int b = blockIdx.y;
    int t0 = blockIdx.x * TT;
    int tid = threadIdx.x;

    // load x-tile, apply carry correction x = xl + A^(j+1) * prev
    for (int idx = tid; idx < TT * N; idx += 128) {
        int tt = idx >> 8;          // N = 256
        int n = idx & (N - 1);
        int t = t0 + tt;
        int j = t & (L - 1);
        int c = t >> LOG2L;
        float2 xv = xbuf[((size_t)b * T + t) * N + n];
        float2 p = Apow[j * N + n];
        float2 v = prevs[((size_t)b * NC + c) * N + n];
        sxr[tt][n] = xv.x + p.x * v.x - p.y * v.y;
        sxi[tt][n] = xv.y + p.x * v.y + p.y * v.x;
    }
    for (int idx = tid; idx < TT * INF; idx += 128) {
        int tt = idx >> 7;          // INF = 128
        int k = idx & (INF - 1);
        su2[tt][k] = u[((size_t)b * T + t0 + tt) * INF + k];
    }
    __syncthreads();

    int o = tid;
    float acc[TT];
    float bv = bias[o];
#pragma unroll
    for (int tt = 0; tt < TT; ++tt) acc[tt] = bv;

    for (int n = 0; n < N; ++n) {
        float cr = Cre[n * OUTF + o];
        float ci = Cim[n * OUTF + o];
#pragma unroll
        for (int tt = 0; tt < TT; ++tt)
            acc[tt] += sxr[tt][n] * cr - sxi[tt][n] * ci;
    }
    for (int k = 0; k < INF; ++k) {
        float dv = D[k * OUTF + o];
#pragma unroll
        for (int tt = 0; tt < TT; ++tt)
            acc[tt] += su2[tt][k] * dv;
    }
#pragma unroll
    for (int tt = 0; tt < TT; ++tt)
        y[((size_t)b * T + t0 + tt) * OUTF + o] = acc[tt];
}

extern "C" void kernel_launch(void* const* d_in, const int* in_sizes, int n_in,
                              void* d_out, int out_size, void* d_ws, size_t ws_size,
                              hipStream_t stream) {
    const float* u    = (const float*)d_in[0];
    const float* x0re = (const float*)d_in[1];
    const float* x0im = (const float*)d_in[2];
    const float* Are  = (const float*)d_in[3];
    const float* Aim  = (const float*)d_in[4];
    const float* Bre  = (const float*)d_in[5];
    const float* Bim  = (const float*)d_in[6];
    const float* Cre  = (const float*)d_in[7];
    const float* Cim  = (const float*)d_in[8];
    const float* D    = (const float*)d_in[9];
    const float* bias = (const float*)d_in[10];
    float* y = (float*)d_out;

    char* ws = (char*)d_ws;
    float2* Apow   = (float2*)ws;                                   // 64 KB
    char* p = ws + (size_t)L * N * sizeof(float2);
    float2* xbuf   = (float2*)p;                                    // 33.5 MB
    p += (size_t)BATCH * T * N * sizeof(float2);
    float2* finals = (float2*)p;                                    // 1 MB
    p += (size_t)BATCH * NC * N * sizeof(float2);
    float2* prevs  = (float2*)p;                                    // 1 MB

    const int ysz = BATCH * T * OUTF;
    const int tail_elems = out_size - ysz;
    // complex64 x_last = B*N*2 floats interleaved if room; else real part only
    int tail_mode = (tail_elems >= BATCH * N * 2) ? 2
                  : (tail_elems >= BATCH * N) ? 1 : 0;
    float* tail = y + ysz;

    k0_powers<<<1, N, 0, stream>>>(Are, Aim, Apow);
    k1_scan<<<dim3(NC, BATCH), 256, 0, stream>>>(u, Bre, Bim, Apow, xbuf, finals);
    k2_carry<<<BATCH, 256, 0, stream>>>(x0re, x0im, Apow, finals, prevs, tail, tail_mode);
    k3_out<<<dim3(T / TT, BATCH), 128, 0, stream>>>(xbuf, Apow, prevs, u, Cre, Cim, D, bias, y);
}